// Round 8
// baseline (196.852 us; speedup 1.0000x reference)
//
#include <hip/hip_runtime.h>
#include <hip/hip_bf16.h>

#define LOG2E 1.4426950408889634f
// reference: mask(-1e9) BEFORE scale(/8); log2e folded into Q pre-scale
#define MASKVAL (-1.25e8f * LOG2E)

typedef __bf16 bf16x8 __attribute__((ext_vector_type(8)));
typedef __bf16 bf16x4 __attribute__((ext_vector_type(4)));
typedef short  shortx4 __attribute__((ext_vector_type(4)));
typedef float  floatx4 __attribute__((ext_vector_type(4)));

__device__ __forceinline__ floatx4 mfma16(bf16x8 a, bf16x8 b, floatx4 c) {
  return __builtin_amdgcn_mfma_f32_16x16x32_bf16(a, b, c, 0, 0, 0);
}

// 16x16x16 bf16 MFMA: B-operand layout (n=l15, k=quad*4+i) == S^T C-tile
// layout -> P feeds PV with zero cross-lane transforms.
__device__ __forceinline__ floatx4 mfma_pv(bf16x4 a, bf16x4 b, floatx4 c) {
#if __has_builtin(__builtin_amdgcn_mfma_f32_16x16x16_bf16)
  return __builtin_amdgcn_mfma_f32_16x16x16_bf16(a, b, c, 0, 0, 0);
#else
  shortx4 as, bs;
  __builtin_memcpy(&as, &a, 8);
  __builtin_memcpy(&bs, &b, 8);
  return __builtin_amdgcn_mfma_f32_16x16x16bf16_1k(as, bs, c, 0, 0, 0);
#endif
}

// async global->LDS, 16B per lane. Dest = wave-uniform base + lane*16.
__device__ __forceinline__ void load_lds16(const __bf16* g, __bf16* l) {
  __builtin_amdgcn_global_load_lds(
      (const __attribute__((address_space(1))) void*)g,
      (__attribute__((address_space(3))) void*)l, 16, 0, 0);
}

// encourage v_max3_f32 fusion
__device__ __forceinline__ float max3f(float a, float b, float c) {
  return fmaxf(a, fmaxf(b, c));
}

// ---------------------------------------------------------------------------
// Fold LoRA into weights, emit W_eff^T bf16 [ncols][1024].  Both weight sets
// in one launch: blockIdx.x < 48 -> qkv (ncols 3072), else proj (ncols 1024).
// ---------------------------------------------------------------------------
__global__ __launch_bounds__(256)
void fold_wt2(const float* __restrict__ Wq, const float* __restrict__ Aq,
              const float* __restrict__ Bq, __bf16* __restrict__ WTq,
              const float* __restrict__ Wp, const float* __restrict__ Ap,
              const float* __restrict__ Bp, __bf16* __restrict__ WTp) {
  __shared__ float tile[64][65];
  __shared__ float sLb[8][64];
  const int bx = blockIdx.x;
  const bool isQ = bx < 48;
  const float* W  = isQ ? Wq : Wp;
  const float* La = isQ ? Aq : Ap;
  const float* Lb = isQ ? Bq : Bp;
  __bf16* WT = isQ ? WTq : WTp;
  const int ncols = isQ ? 3072 : 1024;
  const int nt = (isQ ? bx : bx - 48) * 64;
  const int kt = blockIdx.y * 64;
  const int tid = threadIdx.x;
  const int tx = tid & 63, ty = tid >> 6;

  float rLa[8];
  *(float4*)&rLa[0] = *(const float4*)(La + (size_t)(kt + tx) * 8);
  *(float4*)&rLa[4] = *(const float4*)(La + (size_t)(kt + tx) * 8 + 4);

#pragma unroll
  for (int rep = 0; rep < 2; rep++) {
    int idx = tid + rep * 256;
    sLb[idx >> 6][idx & 63] = Lb[(size_t)(idx >> 6) * ncols + nt + (idx & 63)];
  }
#pragma unroll
  for (int rep = 0; rep < 16; rep++) {
    int i = rep * 4 + ty;
    tile[i][tx] = W[(size_t)(kt + i) * ncols + nt + tx];
  }
  __syncthreads();
#pragma unroll
  for (int rep = 0; rep < 16; rep++) {
    int i = rep * 4 + ty;
    int n = nt + i, k = kt + tx;
    float acc = tile[tx][i];
#pragma unroll
    for (int r = 0; r < 8; r++)
      acc += 2.0f * rLa[r] * sLb[r][i];  // LORA_SCALING = 2
    WT[(size_t)n * 1024 + k] = (__bf16)acc;
  }
}

__global__ __launch_bounds__(256)
void cast_x(const float* __restrict__ x, __bf16* __restrict__ o) {
  int i = blockIdx.x * 256 + threadIdx.x;
  float4 v = ((const float4*)x)[i];
  bf16x4 r = {(__bf16)v.x, (__bf16)v.y, (__bf16)v.z, (__bf16)v.w};
  ((bf16x4*)o)[i] = r;
}

// ---------------------------------------------------------------------------
// Fused QKV projection v2 (unchanged from R7: counted-vmcnt dbuf + LDS
// transpose epilogue).  D[p][s] = sum_k WT[p][k] X[s][k], 128x128 tiles.
// ---------------------------------------------------------------------------
__global__ __launch_bounds__(256)
void gemm_qkv(const __bf16* __restrict__ WT, const __bf16* __restrict__ X,
              const float* __restrict__ bias, __bf16* __restrict__ qk,
              __bf16* __restrict__ vtb) {
  const int K = 1024;
  __shared__ alignas(16) __bf16 smem[32768];  // 64 KB: A0|A1|B0|B1
  const int tid = threadIdx.x;
  const int wave = tid >> 6, lane = tid & 63;
  const int wm = wave >> 1, wn = wave & 1;
  const int quad = lane >> 4, l15 = lane & 15;
  const int p0 = blockIdx.y * 128, s0 = blockIdx.x * 128;
  const int srow8 = lane >> 3, sc8 = lane & 7;
  const int sswz = sc8 ^ srow8;

  auto STAGE = [&](int bb, int kb) {
    __bf16* Ab = smem + bb * 8192;
    __bf16* Bb = smem + 16384 + bb * 8192;
#pragma unroll
    for (int t = 0; t < 4; t++) {
      int rbase = (wave * 4 + t) * 8;
      int row = rbase + srow8;
      load_lds16(WT + (size_t)(p0 + row) * K + kb + sswz * 8, Ab + rbase * 64);
      load_lds16(X + (size_t)(s0 + row) * K + kb + sswz * 8, Bb + rbase * 64);
    }
  };

  floatx4 acc[4][4] = {};
  STAGE(0, 0);

  for (int it = 0; it < 16; it++) {
    const int cur = it & 1;
    if (it < 15) {
      STAGE(cur ^ 1, (it + 1) * 64);
      asm volatile("s_waitcnt vmcnt(8)" ::: "memory");
    } else {
      asm volatile("s_waitcnt vmcnt(0)" ::: "memory");
    }
    __builtin_amdgcn_s_barrier();
    __builtin_amdgcn_sched_barrier(0);
    const __bf16* Ac = smem + cur * 8192;
    const __bf16* Bc = smem + 16384 + cur * 8192;
#pragma unroll
    for (int ks = 0; ks < 2; ks++) {
      bf16x8 af[4], bfv[4];
#pragma unroll
      for (int t = 0; t < 4; t++) {
        int ra = wm * 64 + t * 16 + l15;
        int rb = wn * 64 + t * 16 + l15;
        int ch = (ks * 4 + quad) ^ (l15 & 7);
        af[t]  = *(const bf16x8*)(Ac + ra * 64 + ch * 8);
        bfv[t] = *(const bf16x8*)(Bc + rb * 64 + ch * 8);
      }
#pragma unroll
      for (int mi = 0; mi < 4; mi++)
#pragma unroll
        for (int ni = 0; ni < 4; ni++)
          acc[mi][ni] = mfma16(af[mi], bfv[ni], acc[mi][ni]);
    }
    __builtin_amdgcn_s_barrier();  // all waves done with buf cur
  }

  // ---- coalesced epilogue via LDS transpose (64KB smem now free) ----
  __bf16* ep = smem;
  const int b = s0 >> 11, s2b = s0 & 2047;  // tile fully inside one batch

  if (p0 < 2048) {  // ---- q/k: LDS [token][ch 0..127] -> [tok][dh] rows ----
    const float qscale = (p0 < 1024) ? 0.125f * LOG2E : 1.0f;
#pragma unroll
    for (int mi = 0; mi < 4; mi++) {
      int ch0 = wm * 64 + mi * 16 + quad * 4;
      float4 b4 = *(const float4*)(bias + p0 + ch0);
#pragma unroll
      for (int ni = 0; ni < 4; ni++) {
        int tl = wn * 64 + ni * 16 + l15;
        bf16x4 o = {(__bf16)((acc[mi][ni][0] + b4.x) * qscale),
                    (__bf16)((acc[mi][ni][1] + b4.y) * qscale),
                    (__bf16)((acc[mi][ni][2] + b4.z) * qscale),
                    (__bf16)((acc[mi][ni][3] + b4.w) * qscale)};
        *(bf16x4*)(ep + tl * 136 + ch0) = o;
      }
    }
    __syncthreads();
    const int part = p0 >> 10;
    const int h0 = (p0 & 1023) >> 6;         // tile = heads h0, h0+1
    const int hs = wave & 1, tb = (wave >> 1) * 64;
    __bf16* outp = qk + (size_t)part * 4194304 +
                   ((size_t)((b * 16 + h0 + hs) * 2048 + s2b)) * 64;
#pragma unroll
    for (int j = 0; j < 8; j++) {
      int tok = tb + j * 8 + (lane >> 3);
      int dh = (lane & 7) * 8;
      bf16x8 v = *(const bf16x8*)(ep + tok * 136 + hs * 64 + dh);
      *(bf16x8*)(outp + (size_t)tok * 64 + dh) = v;   // 1KB contig / instr
    }
  } else {  // ---- v: LDS [ch][permuted tok] -> [dh] rows of 256B ----
#pragma unroll
    for (int mi = 0; mi < 4; mi++) {
      int ch0 = wm * 64 + mi * 16 + quad * 4;
      float4 b4 = *(const float4*)(bias + p0 + ch0);
#pragma unroll
      for (int ni = 0; ni < 4; ni++) {
        int tl = wn * 64 + ni * 16 + l15;
        int off = tl & 63, t = off >> 4, qd = (off >> 2) & 3, rr = off & 3;
        int ptl = (tl & 64) | ((t >> 1) * 32 + qd * 8 + (t & 1) * 4 + rr);
        ep[(ch0 + 0) * 136 + ptl] = (__bf16)(acc[mi][ni][0] + b4.x);
        ep[(ch0 + 1) * 136 + ptl] = (__bf16)(acc[mi][ni][1] + b4.y);
        ep[(ch0 + 2) * 136 + ptl] = (__bf16)(acc[mi][ni][2] + b4.z);
        ep[(ch0 + 3) * 136 + ptl] = (__bf16)(acc[mi][ni][3] + b4.w);
      }
    }
    __syncthreads();
    const int h0 = (p0 & 1023) >> 6;
#pragma unroll
    for (int j = 0; j < 8; j++) {
      int ch = wave * 32 + j * 4 + (lane >> 4);
      int to = (lane & 15) * 8;
      bf16x8 v = *(const bf16x8*)(ep + ch * 136 + to);
      int h = h0 + (ch >> 6), dh = ch & 63;
      *(bf16x8*)(vtb + ((size_t)((b * 16 + h) * 64 + dh)) * 2048 + s2b + to) =
          v;  // 4 x 256B runs / instr
    }
  }
}

// ---------------------------------------------------------------------------
// Output projection v2 (unchanged from R7): counted-vmcnt LDS double-buffer.
// ---------------------------------------------------------------------------
__global__ __launch_bounds__(256)
void gemm_proj(const __bf16* __restrict__ A, const __bf16* __restrict__ BT,
               const float* __restrict__ bias, float* __restrict__ Cout, int N) {
  const int K = 1024;
  __shared__ alignas(16) __bf16 smem[24576];  // 48 KB: A0|A1|B0|B1
  const int tid = threadIdx.x;
  const int wave = tid >> 6, lane = tid & 63;
  const int wm = wave >> 1, wn = wave & 1;
  const int quad = lane >> 4, l15 = lane & 15;
  const int m0 = blockIdx.y * 64, n0 = blockIdx.x * 128;
  const int srow8 = lane >> 3, sc8 = lane & 7;
  const int sswz = sc8 ^ srow8;

  auto STAGE = [&](int bb, int kb) {
    __bf16* Ab = smem + bb * 4096;
    __bf16* Bb = smem + 8192 + bb * 8192;
#pragma unroll
    for (int t = 0; t < 2; t++) {
      int rbase = (wave * 2 + t) * 8;
      load_lds16(A + (size_t)(m0 + rbase + srow8) * K + kb + sswz * 8,
                 Ab + rbase * 64);
    }
#pragma unroll
    for (int t = 0; t < 4; t++) {
      int rbase = (wave * 4 + t) * 8;
      load_lds16(BT + (size_t)(n0 + rbase + srow8) * K + kb + sswz * 8,
                 Bb + rbase * 64);
    }
  };

  floatx4 acc[2][4] = {};
  STAGE(0, 0);

  for (int it = 0; it < 16; it++) {
    const int cur = it & 1;
    if (it < 15) {
      STAGE(cur ^ 1, (it + 1) * 64);
      asm volatile("s_waitcnt vmcnt(6)" ::: "memory");
    } else {
      asm volatile("s_waitcnt vmcnt(0)" ::: "memory");
    }
    __builtin_amdgcn_s_barrier();
    __builtin_amdgcn_sched_barrier(0);
    const __bf16* Ac = smem + cur * 4096;
    const __bf16* Bc = smem + 8192 + cur * 8192;
#pragma unroll
    for (int ks = 0; ks < 2; ks++) {
      bf16x8 af[2], bfv[4];
      int ch = (ks * 4 + quad) ^ (l15 & 7);
#pragma unroll
      for (int t = 0; t < 2; t++)
        af[t] = *(const bf16x8*)(Ac + (wm * 32 + t * 16 + l15) * 64 + ch * 8);
#pragma unroll
      for (int t = 0; t < 4; t++)
        bfv[t] = *(const bf16x8*)(Bc + (wn * 64 + t * 16 + l15) * 64 + ch * 8);
#pragma unroll
      for (int mi = 0; mi < 2; mi++)
#pragma unroll
        for (int ni = 0; ni < 4; ni++)
          acc[mi][ni] = mfma16(af[mi], bfv[ni], acc[mi][ni]);
    }
    __builtin_amdgcn_s_barrier();
  }

#pragma unroll
  for (int mi = 0; mi < 2; mi++)
#pragma unroll
    for (int ni = 0; ni < 4; ni++) {
      int n = n0 + wn * 64 + ni * 16 + l15;
#pragma unroll
      for (int r = 0; r < 4; r++) {
        int m = m0 + wm * 32 + mi * 16 + quad * 4 + r;
        Cout[(size_t)m * N + n] = acc[mi][ni][r] + bias[n];
      }
    }
}

// ---------------------------------------------------------------------------
// Causal flash attention v19: DUAL-STRIP blocks (= 128-q tile as two 64-q
// strips sharing the staging pipeline).
// Geometry: adjacent strips (2u, 2u+1) of the same head read the IDENTICAL
// key chunks 0..2u (plus one extra chunk for the odd strip).  One block
// processes both: per chunk, ONE K/V staging + ONE barrier pair + ONE vmcnt
// serve 64 MFMAs (2 strips x QK+PV) instead of 32, and the two softmax
// chains are independent -> ILP fills the serial-latency bubbles that more
// waves (v15) or more uniformity (v14) could not.  Total block-iterations
// drop 16896 -> 8704 (-48%).
// Grid 512 = 16 pairs x 32 bh; pair order u = (g<8) ? 15-g : g-8 makes
// co-resident blocks (bid, bid+256) cost a constant 34 iters, heavy half
// dispatched first.  Grid caps residency at 8 waves/CU, so VGPR can grow to
// ~128 without occupancy cost (v12's trap does not apply here).
// Per-chunk internals = v17 (counted vmcnt(4), XOR-swizzled LDS, pre-scanned
// padding, shuffle-free fast-path softmax, per-quad partial lrun).
// ---------------------------------------------------------------------------
__global__ __launch_bounds__(256)
void flash_attn(const __bf16* __restrict__ q, const __bf16* __restrict__ k,
                const __bf16* __restrict__ vt, const int* __restrict__ amask,
                __bf16* __restrict__ ctx) {
  const int S = 2048;
  __shared__ alignas(16) __bf16 Ks[2][64 * 64];
  __shared__ alignas(16) __bf16 Vs[2][64 * 64];
  const int bid = blockIdx.x;
  const int g = bid >> 5;
  const int u = (g < 8) ? (15 - g) : (g - 8);  // pair idx; (g, g+8) sum const
  const int jA = 2 * u + 1, jB = 2 * u;        // A = long strip, B = short
  const int bh = bid & 31;           // bh%8 = XCD -> per-head K/V L2 locality
  const int b = bh >> 4, h = bh & 15;
  const int wave = threadIdx.x >> 6, lane = threadIdx.x & 63;
  const int quad = lane >> 4, l15 = lane & 15;
  const int srow8 = lane >> 3, sc8 = lane & 7;
  const int sswz = sc8 ^ srow8;
  const int qrowA = jA * 64 + wave * 16 + l15;
  const int qrowB = jB * 64 + wave * 16 + l15;

  const __bf16* qp  = q  + (size_t)bh * S * 64;
  const __bf16* kp0 = k  + (size_t)bh * S * 64;
  const __bf16* vp0 = vt + (size_t)bh * 64 * S;

  // one-time padding pre-scan (int4, over-scan-safe inside row b)
  int anyp = 0;
  const int npre = (jA + 4) >> 2;
  for (int it = 0; it < npre; it++) {
    int4 v = *(const int4*)(amask + b * S + it * 256 + lane * 4);
    anyp |= (v.x == 0) | (v.y == 0) | (v.z == 0) | (v.w == 0);
  }
  const bool padded = (__ballot(anyp) != 0ull);  // block-uniform

  // Q fragments for both strips (issued before STAGE(0))
  bf16x8 qfA[2], qfB[2];
#pragma unroll
  for (int ks = 0; ks < 2; ks++) {
    qfA[ks] = *(const bf16x8*)(qp + (size_t)qrowA * 64 + ks * 32 + quad * 8);
    qfB[ks] = *(const bf16x8*)(qp + (size_t)qrowB * 64 + ks * 32 + quad * 8);
  }

  auto STAGE = [&](int bb, int cc) {
#pragma unroll
    for (int t = 0; t < 2; t++) {
      int rbase = (wave * 2 + t) * 8;
      load_lds16(kp0 + (size_t)cc * 4096 + (size_t)(rbase + srow8) * 64 +
                     sswz * 8,
                 &Ks[bb][rbase * 64]);
    }
#pragma unroll
    for (int t = 0; t < 2; t++) {
      int rbase = (wave * 2 + t) * 8;
      load_lds16(vp0 + (size_t)(rbase + srow8) * S + cc * 64 + sswz * 8,
                 &Vs[bb][rbase * 64]);
    }
  };

  STAGE(0, 0);

  float mrunA = 0.0f, lrunA = 0.0f;  // lrun = per-quad PARTIAL sums
  float mrunB = 0.0f, lrunB = 0.0f;
  floatx4 oaccA[4] = {}, oaccB[4] = {};

  // mask + softmax + pack for one strip (v17 internals)
  auto MASKSM = [&](floatx4 (&st)[4], float& mrun, float& lrun,
                    floatx4 (&oacc)[4], bf16x4 (&pB)[4], int c, int jX) {
    if (padded) {
      int am_c = amask[b * S + c * 64 + lane];  // rare path, latency ok
      unsigned long long pm = __ballot(am_c == 0);
#pragma unroll
      for (int nt = 0; nt < 4; nt++) {
        int kl = nt * 16 + quad * 4;
#pragma unroll
        for (int r = 0; r < 4; r++) {
          bool pad = (pm >> (kl + r)) & 1ull;
          bool masked = pad || ((c == jX) && (kl + r > wave * 16 + l15));
          st[nt][r] = masked ? MASKVAL : st[nt][r];
        }
      }
    } else if (c == jX) {  // diagonal chunk: local causal mask only
#pragma unroll
      for (int nt = 0; nt < 4; nt++) {
        int kl = nt * 16 + quad * 4;
#pragma unroll
        for (int r = 0; r < 4; r++) {
          bool masked = kl + r > wave * 16 + l15;
          st[nt][r] = masked ? MASKVAL : st[nt][r];
        }
      }
    }

    float t0 = max3f(st[0][0], st[0][1], st[0][2]);
    float t1 = max3f(st[0][3], st[1][0], st[1][1]);
    float t2 = max3f(st[1][2], st[1][3], st[2][0]);
    float t3 = max3f(st[2][1], st[2][2], st[2][3]);
    float t4 = max3f(st[3][0], st[3][1], st[3][2]);
    float inm = fmaxf(max3f(t0, t1, t2), max3f(t3, t4, st[3][3]));
#pragma unroll
    for (int nt = 0; nt < 4; nt++)
#pragma unroll
      for (int r = 0; r < 4; r++)
        st[nt][r] = exp2f(st[nt][r] - mrun);  // p vs mrun_old, exact
    float ssum = (((st[0][0] + st[0][1]) + (st[0][2] + st[0][3])) +
                  ((st[1][0] + st[1][1]) + (st[1][2] + st[1][3]))) +
                 (((st[2][0] + st[2][1]) + (st[2][2] + st[2][3])) +
                  ((st[3][0] + st[3][1]) + (st[3][2] + st[3][3])));
    if (!__all(inm - mrun <= 8.0f)) {  // rare rescale (wave-uniform)
      float rm = fmaxf(inm, __shfl_xor(inm, 16, 64));
      rm = fmaxf(rm, __shfl_xor(rm, 32, 64));
      float mnew = fmaxf(mrun, rm);
      float al = exp2f(mrun - mnew);
      mrun = mnew;
      lrun *= al;
      ssum *= al;
#pragma unroll
      for (int nt = 0; nt < 4; nt++)
#pragma unroll
        for (int r = 0; r < 4; r++) st[nt][r] *= al;
#pragma unroll
      for (int nd = 0; nd < 4; nd++)
#pragma unroll
        for (int r = 0; r < 4; r++) oacc[nd][r] *= al;
    }
    lrun += ssum;

#pragma unroll
    for (int nt = 0; nt < 4; nt++) {
      bf16x4 pk = {(__bf16)st[nt][0], (__bf16)st[nt][1],
                   (__bf16)st[nt][2], (__bf16)st[nt][3]};
      pB[nt] = pk;
    }
  };

  // ---- shared chunks 0..jB: both strips per iteration ----
  for (int c = 0; c <= jB; c++) {
    const int cur = c & 1;
    STAGE(cur ^ 1, c + 1);                 // c+1 <= jA always
    asm volatile("s_waitcnt vmcnt(4)" ::: "memory");
    __builtin_amdgcn_s_barrier();          // chunk c data visible to all
    __builtin_amdgcn_sched_barrier(0);     // no ds_read hoist above barrier

    // QK both strips: 8 kf ds_reads feed 32 MFMAs
    floatx4 stA[4] = {}, stB[4] = {};
    __builtin_amdgcn_s_setprio(1);
#pragma unroll
    for (int ks = 0; ks < 2; ks++) {
      const int ch = (ks * 4 + quad) ^ (l15 & 7);
      bf16x8 kf[4];
#pragma unroll
      for (int nt = 0; nt < 4; nt++)
        kf[nt] = *(const bf16x8*)(&Ks[cur][(nt * 16 + l15) * 64 + ch * 8]);
#pragma unroll
      for (int nt = 0; nt < 4; nt++) {
        stA[nt] = mfma16(kf[nt], qfA[ks], stA[nt]);
        stB[nt] = mfma16(kf[nt], qfB[ks], stB[nt]);
      }
    }
    __builtin_amdgcn_s_setprio(0);

    bf16x4 pBA[4], pBB[4];
    MASKSM(stA, mrunA, lrunA, oaccA, pBA, c, jA);  // c < jA: no diag for A
    MASKSM(stB, mrunB, lrunB, oaccB, pBB, c, jB);

    // PV both strips: 8 V ds_reads feed 32 MFMAs
    __builtin_amdgcn_s_setprio(1);
#pragma unroll
    for (int tp = 0; tp < 2; tp++) {
      const int chv = (tp * 4 + quad) ^ (l15 & 7);
#pragma unroll
      for (int nd = 0; nd < 4; nd++) {
        bf16x8 v8 =
            *(const bf16x8*)(&Vs[cur][(nd * 16 + l15) * 64 + chv * 8]);
        bf16x4 vA0 = {v8[0], v8[1], v8[2], v8[3]};
        bf16x4 vA1 = {v8[4], v8[5], v8[6], v8[7]};
        oaccA[nd] = mfma_pv(vA0, pBA[2 * tp], oaccA[nd]);
        oaccB[nd] = mfma_pv(vA0, pBB[2 * tp], oaccB[nd]);
        oaccA[nd] = mfma_pv(vA1, pBA[2 * tp + 1], oaccA[nd]);
        oaccB[nd] = mfma_pv(vA1, pBB[2 * tp + 1], oaccB[nd]);
      }
    }
    __builtin_amdgcn_s_setprio(0);

    __builtin_amdgcn_s_barrier();  // all waves done reading buf cur
  }

  // ---- tail chunk c = jA: strip A only (staged during iter jB) ----
  {
    const int c = jA;
    const int cur = c & 1;
    asm volatile("s_waitcnt vmcnt(0)" ::: "memory");
    __builtin_amdgcn_s_barrier();
    __builtin_amdgcn_sched_barrier(0);

    floatx4 stA[4] = {};
    __builtin_amdgcn_s_setprio(1);
#pragma unroll
    for (int ks = 0; ks < 2; ks++) {
      const int ch = (ks * 4 + quad) ^ (l15 & 7);
      bf16x8 kf[4];
#pragma unroll
      for (int nt = 0; nt < 4; nt++)
        kf[nt] = *(const bf16x8*)(&Ks[cur][(nt * 16 + l15) * 64 + ch * 8]);
#pragma unroll
      for (int nt = 0; nt < 4; nt++)
        stA[nt] = mfma16(kf[nt], qfA[ks], stA[nt]);
    }
    __builtin_amdgcn_s_setprio(0);

    bf16x4 pBA[4];
    MASKSM(stA, mrunA, lrunA, oaccA, pBA, c, jA);  // diagonal for A

    __builtin_amdgcn_s_setprio(1);
#pragma unroll
    for (int tp = 0; tp < 2; tp++) {
      const int chv = (tp * 4 + quad) ^ (l15 & 7);
#pragma unroll
      for (int nd = 0; nd < 4; nd++) {
        bf16x8 v8 =
            *(const bf16x8*)(&Vs[cur][(nd * 16 + l15) * 64 + chv * 8]);
        bf16x4 vA0 = {v8[0], v8[1], v8[2], v8[3]};
        bf16x4 vA1 = {v8[4], v8[5], v8[6], v8[7]};
        oaccA[nd] = mfma_pv(vA0, pBA[2 * tp], oaccA[nd]);
        oaccA[nd] = mfma_pv(vA1, pBA[2 * tp + 1], oaccA[nd]);
      }
    }
    __builtin_amdgcn_s_setprio(0);
  }

  // deferred cross-quad l reductions (once per strip)
  lrunA += __shfl_xor(lrunA, 16, 64);
  lrunA += __shfl_xor(lrunA, 32, 64);
  lrunB += __shfl_xor(lrunB, 16, 64);
  lrunB += __shfl_xor(lrunB, 32, 64);

  // epilogue: direct normalize + store, both strips
  const float linvA = 1.0f / lrunA;
  const float linvB = 1.0f / lrunB;
#pragma unroll
  for (int nd = 0; nd < 4; nd++) {
    bf16x4 oA = {(__bf16)(oaccA[nd][0] * linvA), (__bf16)(oaccA[nd][1] * linvA),
                 (__bf16)(oaccA[nd][2] * linvA), (__bf16)(oaccA[nd][3] * linvA)};
    *(bf16x4*)(ctx + ((size_t)(b * 2048 + qrowA)) * 1024 + h * 64 + nd * 16 +
               quad * 4) = oA;
    bf16x4 oB = {(__bf16)(oaccB[nd][0] * linvB), (__bf16)(oaccB[nd][1] * linvB),
                 (__bf16)(oaccB[nd][2] * linvB), (__bf16)(oaccB[nd][3] * linvB)};
    *(bf16x4*)(ctx + ((size_t)(b * 2048 + qrowB)) * 1024 + h * 64 + nd * 16 +
               quad * 4) = oB;
  }
}

// ---------------------------------------------------------------------------
extern "C" void kernel_launch(void* const* d_in, const int* in_sizes, int n_in,
                              void* d_out, int out_size, void* d_ws, size_t ws_size,
                              hipStream_t stream) {
  const float* x  = (const float*)d_in[0];
  const int*   am = (const int*)d_in[1];
  const float* Wq = (const float*)d_in[2];
  const float* bq = (const float*)d_in[3];
  const float* Aq = (const float*)d_in[4];
  const float* Bq = (const float*)d_in[5];
  const float* Wp = (const float*)d_in[6];
  const float* bp = (const float*)d_in[7];
  const float* Ap = (const float*)d_in[8];
  const float* Bp = (const float*)d_in[9];

  __bf16* wqkvT = (__bf16*)d_ws;                       // [3072][1024]
  __bf16* wpT   = wqkvT + (size_t)3072 * 1024;         // [1024][1024]
  __bf16* xbf   = wpT   + (size_t)1024 * 1024;         // [4096][1024]
  __bf16* qbuf  = xbf   + (size_t)4096 * 1024;         // [2][16][2048][64] (+kbuf)
  __bf16* vtbuf = qbuf  + (size_t)2 * 4194304;         // [2][16][64][2048] permuted
  __bf16* ctxb  = vtbuf + (size_t)4194304;             // [4096][1024]

  fold_wt2<<<dim3(64, 16), 256, 0, stream>>>(Wq, Aq, Bq, wqkvT,
                                             Wp, Ap, Bp, wpT);
  cast_x<<<4096, 256, 0, stream>>>(x, xbf);

  gemm_qkv<<<dim3(32, 24), 256, 0, stream>>>(wqkvT, xbf, bq, qbuf, vtbuf);
  flash_attn<<<512, 256, 0, stream>>>(qbuf, qbuf + 4194304, vtbuf, am, ctxb);
  gemm_proj<<<dim3(8, 64), 256, 0, stream>>>(ctxb, wpT, bp, (float*)d_out, 1024);
}

// Round 9
// 179.552 us; speedup vs baseline: 1.0964x; 1.0964x over previous
//
#include <hip/hip_runtime.h>
#include <hip/hip_bf16.h>

#define LOG2E 1.4426950408889634f
// reference: mask(-1e9) BEFORE scale(/8); log2e folded into Q pre-scale
#define MASKVAL (-1.25e8f * LOG2E)

typedef __bf16 bf16x8 __attribute__((ext_vector_type(8)));
typedef __bf16 bf16x4 __attribute__((ext_vector_type(4)));
typedef short  shortx4 __attribute__((ext_vector_type(4)));
typedef float  floatx4 __attribute__((ext_vector_type(4)));

__device__ __forceinline__ floatx4 mfma16(bf16x8 a, bf16x8 b, floatx4 c) {
  return __builtin_amdgcn_mfma_f32_16x16x32_bf16(a, b, c, 0, 0, 0);
}

// 16x16x16 bf16 MFMA: B-operand layout (n=l15, k=quad*4+i) == S^T C-tile
// layout -> P feeds PV with zero cross-lane transforms.
__device__ __forceinline__ floatx4 mfma_pv(bf16x4 a, bf16x4 b, floatx4 c) {
#if __has_builtin(__builtin_amdgcn_mfma_f32_16x16x16_bf16)
  return __builtin_amdgcn_mfma_f32_16x16x16_bf16(a, b, c, 0, 0, 0);
#else
  shortx4 as, bs;
  __builtin_memcpy(&as, &a, 8);
  __builtin_memcpy(&bs, &b, 8);
  return __builtin_amdgcn_mfma_f32_16x16x16bf16_1k(as, bs, c, 0, 0, 0);
#endif
}

// async global->LDS, 16B per lane. Dest = wave-uniform base + lane*16.
__device__ __forceinline__ void load_lds16(const __bf16* g, __bf16* l) {
  __builtin_amdgcn_global_load_lds(
      (const __attribute__((address_space(1))) void*)g,
      (__attribute__((address_space(3))) void*)l, 16, 0, 0);
}

// encourage v_max3_f32 fusion
__device__ __forceinline__ float max3f(float a, float b, float c) {
  return fmaxf(a, fmaxf(b, c));
}

// raw v_exp_f32 (exp2): inputs here are either <= ~8+eps or ~-1.8e8 (masked),
// both handled exactly by the HW instruction (large negative -> 0).
__device__ __forceinline__ float exp2r(float x) {
  return __builtin_amdgcn_exp2f(x);
}

// ---------------------------------------------------------------------------
// Fold LoRA into weights, emit W_eff^T bf16 [ncols][1024].  Both weight sets
// in one launch: blockIdx.x < 48 -> qkv (ncols 3072), else proj (ncols 1024).
// ---------------------------------------------------------------------------
__global__ __launch_bounds__(256)
void fold_wt2(const float* __restrict__ Wq, const float* __restrict__ Aq,
              const float* __restrict__ Bq, __bf16* __restrict__ WTq,
              const float* __restrict__ Wp, const float* __restrict__ Ap,
              const float* __restrict__ Bp, __bf16* __restrict__ WTp) {
  __shared__ float tile[64][65];
  __shared__ float sLb[8][64];
  const int bx = blockIdx.x;
  const bool isQ = bx < 48;
  const float* W  = isQ ? Wq : Wp;
  const float* La = isQ ? Aq : Ap;
  const float* Lb = isQ ? Bq : Bp;
  __bf16* WT = isQ ? WTq : WTp;
  const int ncols = isQ ? 3072 : 1024;
  const int nt = (isQ ? bx : bx - 48) * 64;
  const int kt = blockIdx.y * 64;
  const int tid = threadIdx.x;
  const int tx = tid & 63, ty = tid >> 6;

  float rLa[8];
  *(float4*)&rLa[0] = *(const float4*)(La + (size_t)(kt + tx) * 8);
  *(float4*)&rLa[4] = *(const float4*)(La + (size_t)(kt + tx) * 8 + 4);

#pragma unroll
  for (int rep = 0; rep < 2; rep++) {
    int idx = tid + rep * 256;
    sLb[idx >> 6][idx & 63] = Lb[(size_t)(idx >> 6) * ncols + nt + (idx & 63)];
  }
#pragma unroll
  for (int rep = 0; rep < 16; rep++) {
    int i = rep * 4 + ty;
    tile[i][tx] = W[(size_t)(kt + i) * ncols + nt + tx];
  }
  __syncthreads();
#pragma unroll
  for (int rep = 0; rep < 16; rep++) {
    int i = rep * 4 + ty;
    int n = nt + i, k = kt + tx;
    float acc = tile[tx][i];
#pragma unroll
    for (int r = 0; r < 8; r++)
      acc += 2.0f * rLa[r] * sLb[r][i];  // LORA_SCALING = 2
    WT[(size_t)n * 1024 + k] = (__bf16)acc;
  }
}

__global__ __launch_bounds__(256)
void cast_x(const float* __restrict__ x, __bf16* __restrict__ o) {
  int i = blockIdx.x * 256 + threadIdx.x;
  float4 v = ((const float4*)x)[i];
  bf16x4 r = {(__bf16)v.x, (__bf16)v.y, (__bf16)v.z, (__bf16)v.w};
  ((bf16x4*)o)[i] = r;
}

// ---------------------------------------------------------------------------
// Fused QKV projection v2 (unchanged from R7: counted-vmcnt dbuf + LDS
// transpose epilogue).  D[p][s] = sum_k WT[p][k] X[s][k], 128x128 tiles.
// ---------------------------------------------------------------------------
__global__ __launch_bounds__(256)
void gemm_qkv(const __bf16* __restrict__ WT, const __bf16* __restrict__ X,
              const float* __restrict__ bias, __bf16* __restrict__ qk,
              __bf16* __restrict__ vtb) {
  const int K = 1024;
  __shared__ alignas(16) __bf16 smem[32768];  // 64 KB: A0|A1|B0|B1
  const int tid = threadIdx.x;
  const int wave = tid >> 6, lane = tid & 63;
  const int wm = wave >> 1, wn = wave & 1;
  const int quad = lane >> 4, l15 = lane & 15;
  const int p0 = blockIdx.y * 128, s0 = blockIdx.x * 128;
  const int srow8 = lane >> 3, sc8 = lane & 7;
  const int sswz = sc8 ^ srow8;

  auto STAGE = [&](int bb, int kb) {
    __bf16* Ab = smem + bb * 8192;
    __bf16* Bb = smem + 16384 + bb * 8192;
#pragma unroll
    for (int t = 0; t < 4; t++) {
      int rbase = (wave * 4 + t) * 8;
      int row = rbase + srow8;
      load_lds16(WT + (size_t)(p0 + row) * K + kb + sswz * 8, Ab + rbase * 64);
      load_lds16(X + (size_t)(s0 + row) * K + kb + sswz * 8, Bb + rbase * 64);
    }
  };

  floatx4 acc[4][4] = {};
  STAGE(0, 0);

  for (int it = 0; it < 16; it++) {
    const int cur = it & 1;
    if (it < 15) {
      STAGE(cur ^ 1, (it + 1) * 64);
      asm volatile("s_waitcnt vmcnt(8)" ::: "memory");
    } else {
      asm volatile("s_waitcnt vmcnt(0)" ::: "memory");
    }
    __builtin_amdgcn_s_barrier();
    __builtin_amdgcn_sched_barrier(0);
    const __bf16* Ac = smem + cur * 8192;
    const __bf16* Bc = smem + 16384 + cur * 8192;
#pragma unroll
    for (int ks = 0; ks < 2; ks++) {
      bf16x8 af[4], bfv[4];
#pragma unroll
      for (int t = 0; t < 4; t++) {
        int ra = wm * 64 + t * 16 + l15;
        int rb = wn * 64 + t * 16 + l15;
        int ch = (ks * 4 + quad) ^ (l15 & 7);
        af[t]  = *(const bf16x8*)(Ac + ra * 64 + ch * 8);
        bfv[t] = *(const bf16x8*)(Bc + rb * 64 + ch * 8);
      }
#pragma unroll
      for (int mi = 0; mi < 4; mi++)
#pragma unroll
        for (int ni = 0; ni < 4; ni++)
          acc[mi][ni] = mfma16(af[mi], bfv[ni], acc[mi][ni]);
    }
    __builtin_amdgcn_s_barrier();  // all waves done with buf cur
  }

  // ---- coalesced epilogue via LDS transpose (64KB smem now free) ----
  __bf16* ep = smem;
  const int b = s0 >> 11, s2b = s0 & 2047;  // tile fully inside one batch

  if (p0 < 2048) {  // ---- q/k: LDS [token][ch 0..127] -> [tok][dh] rows ----
    const float qscale = (p0 < 1024) ? 0.125f * LOG2E : 1.0f;
#pragma unroll
    for (int mi = 0; mi < 4; mi++) {
      int ch0 = wm * 64 + mi * 16 + quad * 4;
      float4 b4 = *(const float4*)(bias + p0 + ch0);
#pragma unroll
      for (int ni = 0; ni < 4; ni++) {
        int tl = wn * 64 + ni * 16 + l15;
        bf16x4 o = {(__bf16)((acc[mi][ni][0] + b4.x) * qscale),
                    (__bf16)((acc[mi][ni][1] + b4.y) * qscale),
                    (__bf16)((acc[mi][ni][2] + b4.z) * qscale),
                    (__bf16)((acc[mi][ni][3] + b4.w) * qscale)};
        *(bf16x4*)(ep + tl * 136 + ch0) = o;
      }
    }
    __syncthreads();
    const int part = p0 >> 10;
    const int h0 = (p0 & 1023) >> 6;         // tile = heads h0, h0+1
    const int hs = wave & 1, tb = (wave >> 1) * 64;
    __bf16* outp = qk + (size_t)part * 4194304 +
                   ((size_t)((b * 16 + h0 + hs) * 2048 + s2b)) * 64;
#pragma unroll
    for (int j = 0; j < 8; j++) {
      int tok = tb + j * 8 + (lane >> 3);
      int dh = (lane & 7) * 8;
      bf16x8 v = *(const bf16x8*)(ep + tok * 136 + hs * 64 + dh);
      *(bf16x8*)(outp + (size_t)tok * 64 + dh) = v;   // 1KB contig / instr
    }
  } else {  // ---- v: LDS [ch][permuted tok] -> [dh] rows of 256B ----
#pragma unroll
    for (int mi = 0; mi < 4; mi++) {
      int ch0 = wm * 64 + mi * 16 + quad * 4;
      float4 b4 = *(const float4*)(bias + p0 + ch0);
#pragma unroll
      for (int ni = 0; ni < 4; ni++) {
        int tl = wn * 64 + ni * 16 + l15;
        int off = tl & 63, t = off >> 4, qd = (off >> 2) & 3, rr = off & 3;
        int ptl = (tl & 64) | ((t >> 1) * 32 + qd * 8 + (t & 1) * 4 + rr);
        ep[(ch0 + 0) * 136 + ptl] = (__bf16)(acc[mi][ni][0] + b4.x);
        ep[(ch0 + 1) * 136 + ptl] = (__bf16)(acc[mi][ni][1] + b4.y);
        ep[(ch0 + 2) * 136 + ptl] = (__bf16)(acc[mi][ni][2] + b4.z);
        ep[(ch0 + 3) * 136 + ptl] = (__bf16)(acc[mi][ni][3] + b4.w);
      }
    }
    __syncthreads();
    const int h0 = (p0 & 1023) >> 6;
#pragma unroll
    for (int j = 0; j < 8; j++) {
      int ch = wave * 32 + j * 4 + (lane >> 4);
      int to = (lane & 15) * 8;
      bf16x8 v = *(const bf16x8*)(ep + ch * 136 + to);
      int h = h0 + (ch >> 6), dh = ch & 63;
      *(bf16x8*)(vtb + ((size_t)((b * 16 + h) * 64 + dh)) * 2048 + s2b + to) =
          v;  // 4 x 256B runs / instr
    }
  }
}

// ---------------------------------------------------------------------------
// Output projection v3: REBUILT on the gemm_qkv chassis.  128x128 tiles,
// grid (32, 8) = 256 blocks = exactly 1/CU, perfectly uniform.  Operands
// swapped so the accumulator's 4-elem axis lies along n: As <- wpT n-rows,
// Bs <- ctx m-rows; C col(l15)=m, row(quad*4+r)=n -> epilogue is 16 float4
// stores per lane (64B-contiguous runs per instruction) instead of 64
// scalar dword stores.  Same counted-vmcnt dbuf main loop as gemm_qkv.
// ---------------------------------------------------------------------------
__global__ __launch_bounds__(256)
void gemm_proj(const __bf16* __restrict__ Actx, const __bf16* __restrict__ BT,
               const float* __restrict__ bias, float* __restrict__ Cout, int N) {
  const int K = 1024;
  __shared__ alignas(16) __bf16 smem[32768];  // 64 KB: A0|A1|B0|B1
  const int tid = threadIdx.x;
  const int wave = tid >> 6, lane = tid & 63;
  const int wm = wave >> 1, wn = wave & 1;
  const int quad = lane >> 4, l15 = lane & 15;
  const int p0 = blockIdx.y * 128;  // n-tile base (wpT rows)
  const int s0 = blockIdx.x * 128;  // m-tile base (ctx rows)
  const int srow8 = lane >> 3, sc8 = lane & 7;
  const int sswz = sc8 ^ srow8;

  auto STAGE = [&](int bb, int kb) {
    __bf16* Ab = smem + bb * 8192;
    __bf16* Bb = smem + 16384 + bb * 8192;
#pragma unroll
    for (int t = 0; t < 4; t++) {
      int rbase = (wave * 4 + t) * 8;
      int row = rbase + srow8;
      load_lds16(BT + (size_t)(p0 + row) * K + kb + sswz * 8, Ab + rbase * 64);
      load_lds16(Actx + (size_t)(s0 + row) * K + kb + sswz * 8,
                 Bb + rbase * 64);
    }
  };

  floatx4 acc[4][4] = {};
  STAGE(0, 0);

  for (int it = 0; it < 16; it++) {
    const int cur = it & 1;
    if (it < 15) {
      STAGE(cur ^ 1, (it + 1) * 64);
      asm volatile("s_waitcnt vmcnt(8)" ::: "memory");
    } else {
      asm volatile("s_waitcnt vmcnt(0)" ::: "memory");
    }
    __builtin_amdgcn_s_barrier();
    __builtin_amdgcn_sched_barrier(0);
    const __bf16* Ac = smem + cur * 8192;
    const __bf16* Bc = smem + 16384 + cur * 8192;
#pragma unroll
    for (int ks = 0; ks < 2; ks++) {
      bf16x8 af[4], bfv[4];
#pragma unroll
      for (int t = 0; t < 4; t++) {
        int ra = wm * 64 + t * 16 + l15;
        int rb = wn * 64 + t * 16 + l15;
        int ch = (ks * 4 + quad) ^ (l15 & 7);
        af[t]  = *(const bf16x8*)(Ac + ra * 64 + ch * 8);
        bfv[t] = *(const bf16x8*)(Bc + rb * 64 + ch * 8);
      }
#pragma unroll
      for (int mi = 0; mi < 4; mi++)
#pragma unroll
        for (int ni = 0; ni < 4; ni++)
          acc[mi][ni] = mfma16(af[mi], bfv[ni], acc[mi][ni]);
    }
    __builtin_amdgcn_s_barrier();  // all waves done with buf cur
  }

  // epilogue: n = p0+wm*64+mi*16+quad*4 (+r along float4), m = s0+wn*64+
  // ni*16+l15 -> one float4 store per (mi,ni); 4 quads cover 64B per m-row.
#pragma unroll
  for (int mi = 0; mi < 4; mi++) {
    int n = p0 + wm * 64 + mi * 16 + quad * 4;
    float4 b4 = *(const float4*)(bias + n);
#pragma unroll
    for (int ni = 0; ni < 4; ni++) {
      int m = s0 + wn * 64 + ni * 16 + l15;
      float4 o = {acc[mi][ni][0] + b4.x, acc[mi][ni][1] + b4.y,
                  acc[mi][ni][2] + b4.z, acc[mi][ni][3] + b4.w};
      *(float4*)(Cout + (size_t)m * N + n) = o;
    }
  }
}

// ---------------------------------------------------------------------------
// Causal flash attention v20 = v17 chassis (proven best: 51.2us) + two
// micro-cuts, NO structure change (v14/v15/v16/v19 all regressed):
//  - chunk loop unrolled 2x so the LDS buffer index is a compile-time
//    literal in each body: Ks[0]/Ks[1] bases fold into ds_read offset
//    immediates computed once, killing the per-iteration cur-mux + address
//    recompute (~15-20 VALU/iter on a 59%-VALU kernel).
//  - exp2f -> __builtin_amdgcn_exp2f (raw v_exp_f32; masked scores map to 0).
// Internals otherwise identical to v17: 1024 blocks x 4 waves, counted
// vmcnt(4), XOR-swizzled LDS, one-time padding pre-scan, shuffle-free
// fast-path softmax (in-lane max + __all), per-quad partial lrun.
// ---------------------------------------------------------------------------
__global__ __launch_bounds__(256)
void flash_attn(const __bf16* __restrict__ q, const __bf16* __restrict__ k,
                const __bf16* __restrict__ vt, const int* __restrict__ amask,
                __bf16* __restrict__ ctx) {
  const int S = 2048;
  __shared__ alignas(16) __bf16 Ks[2][64 * 64];
  __shared__ alignas(16) __bf16 Vs[2][64 * 64];
  const int bid = blockIdx.x;
  const int jb = 31 - (bid >> 5);    // strip, longest first
  const int bh = bid & 31;           // bh%8 = XCD -> per-head K/V L2 locality
  const int b = bh >> 4, h = bh & 15;
  const int wave = threadIdx.x >> 6, lane = threadIdx.x & 63;
  const int quad = lane >> 4, l15 = lane & 15;
  const int srow8 = lane >> 3, sc8 = lane & 7;
  const int sswz = sc8 ^ srow8;
  const int Q0 = jb * 64;
  const int qrow = Q0 + wave * 16 + l15;  // this wave's query rows

  const __bf16* qp  = q  + (size_t)bh * S * 64;
  const __bf16* kp0 = k  + (size_t)bh * S * 64;
  const __bf16* vp0 = vt + (size_t)bh * 64 * S;

  // one-time padding pre-scan (int4 = 4 chunks per lane-load, <=8 iters).
  int anyp = 0;
  const int npre = (jb + 4) >> 2;
  for (int it = 0; it < npre; it++) {
    int4 v = *(const int4*)(amask + b * S + it * 256 + lane * 4);
    anyp |= (v.x == 0) | (v.y == 0) | (v.z == 0) | (v.w == 0);
  }
  const bool padded = (__ballot(anyp) != 0ull);  // block-uniform

  // Q fragments (issued before STAGE(0) -> drained by the first vmcnt)
  bf16x8 qf[2];
#pragma unroll
  for (int ks = 0; ks < 2; ks++)
    qf[ks] = *(const bf16x8*)(qp + (size_t)qrow * 64 + ks * 32 + quad * 8);

  auto STAGE = [&](int bb, int cc) {
#pragma unroll
    for (int t = 0; t < 2; t++) {
      int rbase = (wave * 2 + t) * 8;
      load_lds16(kp0 + (size_t)cc * 4096 + (size_t)(rbase + srow8) * 64 +
                     sswz * 8,
                 &Ks[bb][rbase * 64]);
    }
#pragma unroll
    for (int t = 0; t < 2; t++) {
      int rbase = (wave * 2 + t) * 8;
      load_lds16(vp0 + (size_t)(rbase + srow8) * S + cc * 64 + sswz * 8,
                 &Vs[bb][rbase * 64]);
    }
  };

  STAGE(0, 0);

  float mrun = 0.0f, lrun = 0.0f;  // lrun = per-quad PARTIAL sum
  floatx4 oacc[4] = {};  // [dh-tile]; col(l15)=q, row(quad*4+r)=dh

  // one chunk; cur is a literal at both call sites -> static LDS bases
  auto CHUNK = [&](int c, int cur) {
    if (c < jb) {
      STAGE(cur ^ 1, c + 1);
      // queue = [stage(c) x4 (one iter old), stage(c+1) x4]; drain stage(c)
      asm volatile("s_waitcnt vmcnt(4)" ::: "memory");
    } else {
      asm volatile("s_waitcnt vmcnt(0)" ::: "memory");
    }
    __builtin_amdgcn_s_barrier();          // chunk c data visible to all
    __builtin_amdgcn_sched_barrier(0);     // no ds_read hoist above barrier

    // S^T = K.Q^T: C col(l15)=q, row(quad*4+r)=key
    floatx4 st[4] = {};
    __builtin_amdgcn_s_setprio(1);
#pragma unroll
    for (int ks = 0; ks < 2; ks++) {
      const int ch = (ks * 4 + quad) ^ (l15 & 7);
      bf16x8 kf[4];
#pragma unroll
      for (int nt = 0; nt < 4; nt++)
        kf[nt] = *(const bf16x8*)(&Ks[cur][(nt * 16 + l15) * 64 + ch * 8]);
#pragma unroll
      for (int nt = 0; nt < 4; nt++)
        st[nt] = mfma16(kf[nt], qf[ks], st[nt]);
    }
    __builtin_amdgcn_s_setprio(0);

    // masking: fast path = causal diagonal only (padded is block-uniform)
    if (padded) {
      int am_c = amask[b * S + c * 64 + lane];  // rare path, latency ok
      unsigned long long pm = __ballot(am_c == 0);
#pragma unroll
      for (int nt = 0; nt < 4; nt++) {
        int kl = nt * 16 + quad * 4;
#pragma unroll
        for (int r = 0; r < 4; r++) {
          bool pad = (pm >> (kl + r)) & 1ull;
          bool masked = pad || ((c == jb) && (kl + r > wave * 16 + l15));
          st[nt][r] = masked ? MASKVAL : st[nt][r];
        }
      }
    } else if (c == jb) {  // diagonal chunk: local causal mask only
#pragma unroll
      for (int nt = 0; nt < 4; nt++) {
        int kl = nt * 16 + quad * 4;
#pragma unroll
        for (int r = 0; r < 4; r++) {
          bool masked = kl + r > wave * 16 + l15;
          st[nt][r] = masked ? MASKVAL : st[nt][r];
        }
      }
    }

    // shuffle-free fast-path softmax (log2 domain, per q = l15)
    float t0 = max3f(st[0][0], st[0][1], st[0][2]);
    float t1 = max3f(st[0][3], st[1][0], st[1][1]);
    float t2 = max3f(st[1][2], st[1][3], st[2][0]);
    float t3 = max3f(st[2][1], st[2][2], st[2][3]);
    float t4 = max3f(st[3][0], st[3][1], st[3][2]);
    float inm = fmaxf(max3f(t0, t1, t2), max3f(t3, t4, st[3][3]));
#pragma unroll
    for (int nt = 0; nt < 4; nt++)
#pragma unroll
      for (int r = 0; r < 4; r++)
        st[nt][r] = exp2r(st[nt][r] - mrun);  // p vs mrun_old, exact
    float ssum = (((st[0][0] + st[0][1]) + (st[0][2] + st[0][3])) +
                  ((st[1][0] + st[1][1]) + (st[1][2] + st[1][3]))) +
                 (((st[2][0] + st[2][1]) + (st[2][2] + st[2][3])) +
                  ((st[3][0] + st[3][1]) + (st[3][2] + st[3][3])));
    if (!__all(inm - mrun <= 8.0f)) {  // rare rescale (wave-uniform)
      float rm = fmaxf(inm, __shfl_xor(inm, 16, 64));
      rm = fmaxf(rm, __shfl_xor(rm, 32, 64));
      float mnew = fmaxf(mrun, rm);
      float al = exp2r(mrun - mnew);
      mrun = mnew;
      lrun *= al;
      ssum *= al;
#pragma unroll
      for (int nt = 0; nt < 4; nt++)
#pragma unroll
        for (int r = 0; r < 4; r++) st[nt][r] *= al;
#pragma unroll
      for (int nd = 0; nd < 4; nd++)
#pragma unroll
        for (int r = 0; r < 4; r++) oacc[nd][r] *= al;
    }
    lrun += ssum;

    // pack P tiles (B-operand == C-layout)
    bf16x4 pB[4];
#pragma unroll
    for (int nt = 0; nt < 4; nt++) {
      bf16x4 pk = {(__bf16)st[nt][0], (__bf16)st[nt][1],
                   (__bf16)st[nt][2], (__bf16)st[nt][3]};
      pB[nt] = pk;
    }

    // O^T += V^T P^T ; one 16B V frag feeds key-subtiles 2tp and 2tp+1
    __builtin_amdgcn_s_setprio(1);
#pragma unroll
    for (int tp = 0; tp < 2; tp++) {
      const int chv = (tp * 4 + quad) ^ (l15 & 7);
#pragma unroll
      for (int nd = 0; nd < 4; nd++) {
        bf16x8 v8 =
            *(const bf16x8*)(&Vs[cur][(nd * 16 + l15) * 64 + chv * 8]);
        bf16x4 vA0 = {v8[0], v8[1], v8[2], v8[3]};
        bf16x4 vA1 = {v8[4], v8[5], v8[6], v8[7]};
        oacc[nd] = mfma_pv(vA0, pB[2 * tp], oacc[nd]);
        oacc[nd] = mfma_pv(vA1, pB[2 * tp + 1], oacc[nd]);
      }
    }
    __builtin_amdgcn_s_setprio(0);

    __builtin_amdgcn_s_barrier();  // all waves done reading buf cur
  };

  // 2x-unrolled chunk loop: buffer index static per body (chunk c -> c&1)
  for (int c = 0; c <= jb; c += 2) {
    CHUNK(c, 0);
    if (c + 1 <= jb) CHUNK(c + 1, 1);
  }

  // deferred cross-quad l reduction (once per strip instead of per chunk)
  lrun += __shfl_xor(lrun, 16, 64);
  lrun += __shfl_xor(lrun, 32, 64);

  // epilogue: direct normalize + store (no merge).
  const float linv = 1.0f / lrun;
#pragma unroll
  for (int nd = 0; nd < 4; nd++) {
    bf16x4 o = {(__bf16)(oacc[nd][0] * linv), (__bf16)(oacc[nd][1] * linv),
                (__bf16)(oacc[nd][2] * linv), (__bf16)(oacc[nd][3] * linv)};
    *(bf16x4*)(ctx + ((size_t)(b * 2048 + qrow)) * 1024 + h * 64 + nd * 16 +
               quad * 4) = o;
  }
}

// ---------------------------------------------------------------------------
extern "C" void kernel_launch(void* const* d_in, const int* in_sizes, int n_in,
                              void* d_out, int out_size, void* d_ws, size_t ws_size,
                              hipStream_t stream) {
  const float* x  = (const float*)d_in[0];
  const int*   am = (const int*)d_in[1];
  const float* Wq = (const float*)d_in[2];
  const float* bq = (const float*)d_in[3];
  const float* Aq = (const float*)d_in[4];
  const float* Bq = (const float*)d_in[5];
  const float* Wp = (const float*)d_in[6];
  const float* bp = (const float*)d_in[7];
  const float* Ap = (const float*)d_in[8];
  const float* Bp = (const float*)d_in[9];

  __bf16* wqkvT = (__bf16*)d_ws;                       // [3072][1024]
  __bf16* wpT   = wqkvT + (size_t)3072 * 1024;         // [1024][1024]
  __bf16* xbf   = wpT   + (size_t)1024 * 1024;         // [4096][1024]
  __bf16* qbuf  = xbf   + (size_t)4096 * 1024;         // [2][16][2048][64] (+kbuf)
  __bf16* vtbuf = qbuf  + (size_t)2 * 4194304;         // [2][16][64][2048] permuted
  __bf16* ctxb  = vtbuf + (size_t)4194304;             // [4096][1024]

  fold_wt2<<<dim3(64, 16), 256, 0, stream>>>(Wq, Aq, Bq, wqkvT,
                                             Wp, Ap, Bp, wpT);
  cast_x<<<4096, 256, 0, stream>>>(x, xbf);

  gemm_qkv<<<dim3(32, 24), 256, 0, stream>>>(wqkvT, xbf, bq, qbuf, vtbuf);
  flash_attn<<<1024, 256, 0, stream>>>(qbuf, qbuf + 4194304, vtbuf, am, ctxb);
  gemm_proj<<<dim3(32, 8), 256, 0, stream>>>(ctxb, wpT, bp, (float*)d_out, 1024);
}

// Round 10
// 172.579 us; speedup vs baseline: 1.1406x; 1.0404x over previous
//
#include <hip/hip_runtime.h>
#include <hip/hip_bf16.h>

#define LOG2E 1.4426950408889634f
// reference: mask(-1e9) BEFORE scale(/8); log2e folded into Q pre-scale
#define MASKVAL (-1.25e8f * LOG2E)

typedef __bf16 bf16x8 __attribute__((ext_vector_type(8)));
typedef __bf16 bf16x4 __attribute__((ext_vector_type(4)));
typedef short  shortx4 __attribute__((ext_vector_type(4)));
typedef float  floatx4 __attribute__((ext_vector_type(4)));

__device__ __forceinline__ floatx4 mfma16(bf16x8 a, bf16x8 b, floatx4 c) {
  return __builtin_amdgcn_mfma_f32_16x16x32_bf16(a, b, c, 0, 0, 0);
}

// 16x16x16 bf16 MFMA: B-operand layout (n=l15, k=quad*4+i) == S^T C-tile
// layout -> P feeds PV with zero cross-lane transforms.
__device__ __forceinline__ floatx4 mfma_pv(bf16x4 a, bf16x4 b, floatx4 c) {
#if __has_builtin(__builtin_amdgcn_mfma_f32_16x16x16_bf16)
  return __builtin_amdgcn_mfma_f32_16x16x16_bf16(a, b, c, 0, 0, 0);
#else
  shortx4 as, bs;
  __builtin_memcpy(&as, &a, 8);
  __builtin_memcpy(&bs, &b, 8);
  return __builtin_amdgcn_mfma_f32_16x16x16bf16_1k(as, bs, c, 0, 0, 0);
#endif
}

// async global->LDS, 16B per lane. Dest = wave-uniform base + lane*16.
__device__ __forceinline__ void load_lds16(const __bf16* g, __bf16* l) {
  __builtin_amdgcn_global_load_lds(
      (const __attribute__((address_space(1))) void*)g,
      (__attribute__((address_space(3))) void*)l, 16, 0, 0);
}

// encourage v_max3_f32 fusion
__device__ __forceinline__ float max3f(float a, float b, float c) {
  return fmaxf(a, fmaxf(b, c));
}

// raw v_exp_f32 (exp2): inputs here are either <= ~8+eps or ~-1.8e8 (masked),
// both handled exactly by the HW instruction (large negative -> 0).
__device__ __forceinline__ float exp2r(float x) {
  return __builtin_amdgcn_exp2f(x);
}

// ---------------------------------------------------------------------------
// Fused (fold_wt2 + cast_x) in ONE launch: bid < 1024 -> LoRA-fold a 64x64
// weight tile (bx=bid&63, by=bid>>6); bid >= 1024 -> cast a 1024-float slab
// of x.  Saves one kernel-launch gap; bodies unchanged from R9.
// ---------------------------------------------------------------------------
__global__ __launch_bounds__(256)
void fold_cast(const float* __restrict__ Wq, const float* __restrict__ Aq,
               const float* __restrict__ Bq, __bf16* __restrict__ WTq,
               const float* __restrict__ Wp, const float* __restrict__ Ap,
               const float* __restrict__ Bp, __bf16* __restrict__ WTp,
               const float* __restrict__ x, __bf16* __restrict__ xo) {
  const int bid = blockIdx.x;
  const int tid = threadIdx.x;
  if (bid >= 1024) {  // ---- cast_x part ----
    int i = (bid - 1024) * 256 + tid;
    float4 v = ((const float4*)x)[i];
    bf16x4 r = {(__bf16)v.x, (__bf16)v.y, (__bf16)v.z, (__bf16)v.w};
    ((bf16x4*)xo)[i] = r;
    return;
  }
  // ---- fold_wt2 part ----
  __shared__ float tile[64][65];
  __shared__ float sLb[8][64];
  const int bx = bid & 63;
  const bool isQ = bx < 48;
  const float* W  = isQ ? Wq : Wp;
  const float* La = isQ ? Aq : Ap;
  const float* Lb = isQ ? Bq : Bp;
  __bf16* WT = isQ ? WTq : WTp;
  const int ncols = isQ ? 3072 : 1024;
  const int nt = (isQ ? bx : bx - 48) * 64;
  const int kt = (bid >> 6) * 64;
  const int tx = tid & 63, ty = tid >> 6;

  float rLa[8];
  *(float4*)&rLa[0] = *(const float4*)(La + (size_t)(kt + tx) * 8);
  *(float4*)&rLa[4] = *(const float4*)(La + (size_t)(kt + tx) * 8 + 4);

#pragma unroll
  for (int rep = 0; rep < 2; rep++) {
    int idx = tid + rep * 256;
    sLb[idx >> 6][idx & 63] = Lb[(size_t)(idx >> 6) * ncols + nt + (idx & 63)];
  }
#pragma unroll
  for (int rep = 0; rep < 16; rep++) {
    int i = rep * 4 + ty;
    tile[i][tx] = W[(size_t)(kt + i) * ncols + nt + tx];
  }
  __syncthreads();
#pragma unroll
  for (int rep = 0; rep < 16; rep++) {
    int i = rep * 4 + ty;
    int n = nt + i, k = kt + tx;
    float acc = tile[tx][i];
#pragma unroll
    for (int r = 0; r < 8; r++)
      acc += 2.0f * rLa[r] * sLb[r][i];  // LORA_SCALING = 2
    WT[(size_t)n * 1024 + k] = (__bf16)acc;
  }
}

// ---------------------------------------------------------------------------
// Fused QKV projection v2 (unchanged from R7: counted-vmcnt dbuf + LDS
// transpose epilogue).  D[p][s] = sum_k WT[p][k] X[s][k], 128x128 tiles.
// ---------------------------------------------------------------------------
__global__ __launch_bounds__(256)
void gemm_qkv(const __bf16* __restrict__ WT, const __bf16* __restrict__ X,
              const float* __restrict__ bias, __bf16* __restrict__ qk,
              __bf16* __restrict__ vtb) {
  const int K = 1024;
  __shared__ alignas(16) __bf16 smem[32768];  // 64 KB: A0|A1|B0|B1
  const int tid = threadIdx.x;
  const int wave = tid >> 6, lane = tid & 63;
  const int wm = wave >> 1, wn = wave & 1;
  const int quad = lane >> 4, l15 = lane & 15;
  const int p0 = blockIdx.y * 128, s0 = blockIdx.x * 128;
  const int srow8 = lane >> 3, sc8 = lane & 7;
  const int sswz = sc8 ^ srow8;

  auto STAGE = [&](int bb, int kb) {
    __bf16* Ab = smem + bb * 8192;
    __bf16* Bb = smem + 16384 + bb * 8192;
#pragma unroll
    for (int t = 0; t < 4; t++) {
      int rbase = (wave * 4 + t) * 8;
      int row = rbase + srow8;
      load_lds16(WT + (size_t)(p0 + row) * K + kb + sswz * 8, Ab + rbase * 64);
      load_lds16(X + (size_t)(s0 + row) * K + kb + sswz * 8, Bb + rbase * 64);
    }
  };

  floatx4 acc[4][4] = {};
  STAGE(0, 0);

  for (int it = 0; it < 16; it++) {
    const int cur = it & 1;
    if (it < 15) {
      STAGE(cur ^ 1, (it + 1) * 64);
      asm volatile("s_waitcnt vmcnt(8)" ::: "memory");
    } else {
      asm volatile("s_waitcnt vmcnt(0)" ::: "memory");
    }
    __builtin_amdgcn_s_barrier();
    __builtin_amdgcn_sched_barrier(0);
    const __bf16* Ac = smem + cur * 8192;
    const __bf16* Bc = smem + 16384 + cur * 8192;
#pragma unroll
    for (int ks = 0; ks < 2; ks++) {
      bf16x8 af[4], bfv[4];
#pragma unroll
      for (int t = 0; t < 4; t++) {
        int ra = wm * 64 + t * 16 + l15;
        int rb = wn * 64 + t * 16 + l15;
        int ch = (ks * 4 + quad) ^ (l15 & 7);
        af[t]  = *(const bf16x8*)(Ac + ra * 64 + ch * 8);
        bfv[t] = *(const bf16x8*)(Bc + rb * 64 + ch * 8);
      }
#pragma unroll
      for (int mi = 0; mi < 4; mi++)
#pragma unroll
        for (int ni = 0; ni < 4; ni++)
          acc[mi][ni] = mfma16(af[mi], bfv[ni], acc[mi][ni]);
    }
    __builtin_amdgcn_s_barrier();  // all waves done with buf cur
  }

  // ---- coalesced epilogue via LDS transpose (64KB smem now free) ----
  __bf16* ep = smem;
  const int b = s0 >> 11, s2b = s0 & 2047;  // tile fully inside one batch

  if (p0 < 2048) {  // ---- q/k: LDS [token][ch 0..127] -> [tok][dh] rows ----
    const float qscale = (p0 < 1024) ? 0.125f * LOG2E : 1.0f;
#pragma unroll
    for (int mi = 0; mi < 4; mi++) {
      int ch0 = wm * 64 + mi * 16 + quad * 4;
      float4 b4 = *(const float4*)(bias + p0 + ch0);
#pragma unroll
      for (int ni = 0; ni < 4; ni++) {
        int tl = wn * 64 + ni * 16 + l15;
        bf16x4 o = {(__bf16)((acc[mi][ni][0] + b4.x) * qscale),
                    (__bf16)((acc[mi][ni][1] + b4.y) * qscale),
                    (__bf16)((acc[mi][ni][2] + b4.z) * qscale),
                    (__bf16)((acc[mi][ni][3] + b4.w) * qscale)};
        *(bf16x4*)(ep + tl * 136 + ch0) = o;
      }
    }
    __syncthreads();
    const int part = p0 >> 10;
    const int h0 = (p0 & 1023) >> 6;         // tile = heads h0, h0+1
    const int hs = wave & 1, tb = (wave >> 1) * 64;
    __bf16* outp = qk + (size_t)part * 4194304 +
                   ((size_t)((b * 16 + h0 + hs) * 2048 + s2b)) * 64;
#pragma unroll
    for (int j = 0; j < 8; j++) {
      int tok = tb + j * 8 + (lane >> 3);
      int dh = (lane & 7) * 8;
      bf16x8 v = *(const bf16x8*)(ep + tok * 136 + hs * 64 + dh);
      *(bf16x8*)(outp + (size_t)tok * 64 + dh) = v;   // 1KB contig / instr
    }
  } else {  // ---- v: LDS [ch][permuted tok] -> [dh] rows of 256B ----
#pragma unroll
    for (int mi = 0; mi < 4; mi++) {
      int ch0 = wm * 64 + mi * 16 + quad * 4;
      float4 b4 = *(const float4*)(bias + p0 + ch0);
#pragma unroll
      for (int ni = 0; ni < 4; ni++) {
        int tl = wn * 64 + ni * 16 + l15;
        int off = tl & 63, t = off >> 4, qd = (off >> 2) & 3, rr = off & 3;
        int ptl = (tl & 64) | ((t >> 1) * 32 + qd * 8 + (t & 1) * 4 + rr);
        ep[(ch0 + 0) * 136 + ptl] = (__bf16)(acc[mi][ni][0] + b4.x);
        ep[(ch0 + 1) * 136 + ptl] = (__bf16)(acc[mi][ni][1] + b4.y);
        ep[(ch0 + 2) * 136 + ptl] = (__bf16)(acc[mi][ni][2] + b4.z);
        ep[(ch0 + 3) * 136 + ptl] = (__bf16)(acc[mi][ni][3] + b4.w);
      }
    }
    __syncthreads();
    const int h0 = (p0 & 1023) >> 6;
#pragma unroll
    for (int j = 0; j < 8; j++) {
      int ch = wave * 32 + j * 4 + (lane >> 4);
      int to = (lane & 15) * 8;
      bf16x8 v = *(const bf16x8*)(ep + ch * 136 + to);
      int h = h0 + (ch >> 6), dh = ch & 63;
      *(bf16x8*)(vtb + ((size_t)((b * 16 + h) * 64 + dh)) * 2048 + s2b + to) =
          v;  // 4 x 256B runs / instr
    }
  }
}

// ---------------------------------------------------------------------------
// Output projection v4: 64x128 tiles -> grid (32,16) = 512 blocks = 2/CU.
// R9 post-mortem: v3's 128x128 tiles gave 256 blocks = 1 block/CU, leaving
// the counted-vmcnt loop's barrier chain fully latency-exposed (est ~40us).
// v4 restores 2 blocks/CU (R7 geometry) while KEEPING the swapped
// orientation (As <- wpT n-rows, Bs <- ctx m-rows) so the accumulator's
// 4-elem axis lies along n -> float4 stores, 64B-contiguous runs per instr.
// ---------------------------------------------------------------------------
__global__ __launch_bounds__(256)
void gemm_proj(const __bf16* __restrict__ Actx, const __bf16* __restrict__ BT,
               const float* __restrict__ bias, float* __restrict__ Cout, int N) {
  const int K = 1024;
  __shared__ alignas(16) __bf16 smem[24576];  // 48 KB: A0|A1|B0|B1
  const int tid = threadIdx.x;
  const int wave = tid >> 6, lane = tid & 63;
  const int wm = wave >> 1, wn = wave & 1;
  const int quad = lane >> 4, l15 = lane & 15;
  const int p0 = blockIdx.y * 64;   // n-tile base (wpT rows)
  const int s0 = blockIdx.x * 128;  // m-tile base (ctx rows)
  const int srow8 = lane >> 3, sc8 = lane & 7;
  const int sswz = sc8 ^ srow8;

  auto STAGE = [&](int bb, int kb) {
    __bf16* Ab = smem + bb * 4096;
    __bf16* Bb = smem + 8192 + bb * 8192;
#pragma unroll
    for (int t = 0; t < 2; t++) {
      int rbase = (wave * 2 + t) * 8;
      load_lds16(BT + (size_t)(p0 + rbase + srow8) * K + kb + sswz * 8,
                 Ab + rbase * 64);
    }
#pragma unroll
    for (int t = 0; t < 4; t++) {
      int rbase = (wave * 4 + t) * 8;
      load_lds16(Actx + (size_t)(s0 + rbase + srow8) * K + kb + sswz * 8,
                 Bb + rbase * 64);
    }
  };

  floatx4 acc[2][4] = {};
  STAGE(0, 0);

  for (int it = 0; it < 16; it++) {
    const int cur = it & 1;
    if (it < 15) {
      STAGE(cur ^ 1, (it + 1) * 64);
      asm volatile("s_waitcnt vmcnt(6)" ::: "memory");
    } else {
      asm volatile("s_waitcnt vmcnt(0)" ::: "memory");
    }
    __builtin_amdgcn_s_barrier();
    __builtin_amdgcn_sched_barrier(0);
    const __bf16* Ac = smem + cur * 4096;
    const __bf16* Bc = smem + 8192 + cur * 8192;
#pragma unroll
    for (int ks = 0; ks < 2; ks++) {
      bf16x8 af[2], bfv[4];
      int ch = (ks * 4 + quad) ^ (l15 & 7);
#pragma unroll
      for (int t = 0; t < 2; t++)
        af[t] = *(const bf16x8*)(Ac + (wm * 32 + t * 16 + l15) * 64 + ch * 8);
#pragma unroll
      for (int t = 0; t < 4; t++)
        bfv[t] = *(const bf16x8*)(Bc + (wn * 64 + t * 16 + l15) * 64 + ch * 8);
#pragma unroll
      for (int mi = 0; mi < 2; mi++)
#pragma unroll
        for (int ni = 0; ni < 4; ni++)
          acc[mi][ni] = mfma16(af[mi], bfv[ni], acc[mi][ni]);
    }
    __builtin_amdgcn_s_barrier();
  }

  // epilogue: n = p0+wm*32+mi*16+quad*4 (+r along float4), m = s0+wn*64+
  // ni*16+l15 -> one float4 store per (mi,ni), 64B-contiguous per quad-set.
#pragma unroll
  for (int mi = 0; mi < 2; mi++) {
    int n = p0 + wm * 32 + mi * 16 + quad * 4;
    float4 b4 = *(const float4*)(bias + n);
#pragma unroll
    for (int ni = 0; ni < 4; ni++) {
      int m = s0 + wn * 64 + ni * 16 + l15;
      float4 o = {acc[mi][ni][0] + b4.x, acc[mi][ni][1] + b4.y,
                  acc[mi][ni][2] + b4.z, acc[mi][ni][3] + b4.w};
      *(float4*)(Cout + (size_t)m * N + n) = o;
    }
  }
}

// ---------------------------------------------------------------------------
// Causal flash attention v20 (unchanged from R9, proven 45.5us): v17 chassis,
// 2x-unrolled chunk loop (static LDS buffer bases), raw v_exp_f32,
// shuffle-free fast-path softmax, counted vmcnt(4), pre-scanned padding.
// ---------------------------------------------------------------------------
__global__ __launch_bounds__(256)
void flash_attn(const __bf16* __restrict__ q, const __bf16* __restrict__ k,
                const __bf16* __restrict__ vt, const int* __restrict__ amask,
                __bf16* __restrict__ ctx) {
  const int S = 2048;
  __shared__ alignas(16) __bf16 Ks[2][64 * 64];
  __shared__ alignas(16) __bf16 Vs[2][64 * 64];
  const int bid = blockIdx.x;
  const int jb = 31 - (bid >> 5);    // strip, longest first
  const int bh = bid & 31;           // bh%8 = XCD -> per-head K/V L2 locality
  const int b = bh >> 4, h = bh & 15;
  const int wave = threadIdx.x >> 6, lane = threadIdx.x & 63;
  const int quad = lane >> 4, l15 = lane & 15;
  const int srow8 = lane >> 3, sc8 = lane & 7;
  const int sswz = sc8 ^ srow8;
  const int Q0 = jb * 64;
  const int qrow = Q0 + wave * 16 + l15;  // this wave's query rows

  const __bf16* qp  = q  + (size_t)bh * S * 64;
  const __bf16* kp0 = k  + (size_t)bh * S * 64;
  const __bf16* vp0 = vt + (size_t)bh * 64 * S;

  // one-time padding pre-scan (int4 = 4 chunks per lane-load, <=8 iters).
  int anyp = 0;
  const int npre = (jb + 4) >> 2;
  for (int it = 0; it < npre; it++) {
    int4 v = *(const int4*)(amask + b * S + it * 256 + lane * 4);
    anyp |= (v.x == 0) | (v.y == 0) | (v.z == 0) | (v.w == 0);
  }
  const bool padded = (__ballot(anyp) != 0ull);  // block-uniform

  // Q fragments (issued before STAGE(0) -> drained by the first vmcnt)
  bf16x8 qf[2];
#pragma unroll
  for (int ks = 0; ks < 2; ks++)
    qf[ks] = *(const bf16x8*)(qp + (size_t)qrow * 64 + ks * 32 + quad * 8);

  auto STAGE = [&](int bb, int cc) {
#pragma unroll
    for (int t = 0; t < 2; t++) {
      int rbase = (wave * 2 + t) * 8;
      load_lds16(kp0 + (size_t)cc * 4096 + (size_t)(rbase + srow8) * 64 +
                     sswz * 8,
                 &Ks[bb][rbase * 64]);
    }
#pragma unroll
    for (int t = 0; t < 2; t++) {
      int rbase = (wave * 2 + t) * 8;
      load_lds16(vp0 + (size_t)(rbase + srow8) * S + cc * 64 + sswz * 8,
                 &Vs[bb][rbase * 64]);
    }
  };

  STAGE(0, 0);

  float mrun = 0.0f, lrun = 0.0f;  // lrun = per-quad PARTIAL sum
  floatx4 oacc[4] = {};  // [dh-tile]; col(l15)=q, row(quad*4+r)=dh

  // one chunk; cur is a literal at both call sites -> static LDS bases
  auto CHUNK = [&](int c, int cur) {
    if (c < jb) {
      STAGE(cur ^ 1, c + 1);
      // queue = [stage(c) x4 (one iter old), stage(c+1) x4]; drain stage(c)
      asm volatile("s_waitcnt vmcnt(4)" ::: "memory");
    } else {
      asm volatile("s_waitcnt vmcnt(0)" ::: "memory");
    }
    __builtin_amdgcn_s_barrier();          // chunk c data visible to all
    __builtin_amdgcn_sched_barrier(0);     // no ds_read hoist above barrier

    // S^T = K.Q^T: C col(l15)=q, row(quad*4+r)=key
    floatx4 st[4] = {};
    __builtin_amdgcn_s_setprio(1);
#pragma unroll
    for (int ks = 0; ks < 2; ks++) {
      const int ch = (ks * 4 + quad) ^ (l15 & 7);
      bf16x8 kf[4];
#pragma unroll
      for (int nt = 0; nt < 4; nt++)
        kf[nt] = *(const bf16x8*)(&Ks[cur][(nt * 16 + l15) * 64 + ch * 8]);
#pragma unroll
      for (int nt = 0; nt < 4; nt++)
        st[nt] = mfma16(kf[nt], qf[ks], st[nt]);
    }
    __builtin_amdgcn_s_setprio(0);

    // masking: fast path = causal diagonal only (padded is block-uniform)
    if (padded) {
      int am_c = amask[b * S + c * 64 + lane];  // rare path, latency ok
      unsigned long long pm = __ballot(am_c == 0);
#pragma unroll
      for (int nt = 0; nt < 4; nt++) {
        int kl = nt * 16 + quad * 4;
#pragma unroll
        for (int r = 0; r < 4; r++) {
          bool pad = (pm >> (kl + r)) & 1ull;
          bool masked = pad || ((c == jb) && (kl + r > wave * 16 + l15));
          st[nt][r] = masked ? MASKVAL : st[nt][r];
        }
      }
    } else if (c == jb) {  // diagonal chunk: local causal mask only
#pragma unroll
      for (int nt = 0; nt < 4; nt++) {
        int kl = nt * 16 + quad * 4;
#pragma unroll
        for (int r = 0; r < 4; r++) {
          bool masked = kl + r > wave * 16 + l15;
          st[nt][r] = masked ? MASKVAL : st[nt][r];
        }
      }
    }

    // shuffle-free fast-path softmax (log2 domain, per q = l15)
    float t0 = max3f(st[0][0], st[0][1], st[0][2]);
    float t1 = max3f(st[0][3], st[1][0], st[1][1]);
    float t2 = max3f(st[1][2], st[1][3], st[2][0]);
    float t3 = max3f(st[2][1], st[2][2], st[2][3]);
    float t4 = max3f(st[3][0], st[3][1], st[3][2]);
    float inm = fmaxf(max3f(t0, t1, t2), max3f(t3, t4, st[3][3]));
#pragma unroll
    for (int nt = 0; nt < 4; nt++)
#pragma unroll
      for (int r = 0; r < 4; r++)
        st[nt][r] = exp2r(st[nt][r] - mrun);  // p vs mrun_old, exact
    float ssum = (((st[0][0] + st[0][1]) + (st[0][2] + st[0][3])) +
                  ((st[1][0] + st[1][1]) + (st[1][2] + st[1][3]))) +
                 (((st[2][0] + st[2][1]) + (st[2][2] + st[2][3])) +
                  ((st[3][0] + st[3][1]) + (st[3][2] + st[3][3])));
    if (!__all(inm - mrun <= 8.0f)) {  // rare rescale (wave-uniform)
      float rm = fmaxf(inm, __shfl_xor(inm, 16, 64));
      rm = fmaxf(rm, __shfl_xor(rm, 32, 64));
      float mnew = fmaxf(mrun, rm);
      float al = exp2r(mrun - mnew);
      mrun = mnew;
      lrun *= al;
      ssum *= al;
#pragma unroll
      for (int nt = 0; nt < 4; nt++)
#pragma unroll
        for (int r = 0; r < 4; r++) st[nt][r] *= al;
#pragma unroll
      for (int nd = 0; nd < 4; nd++)
#pragma unroll
        for (int r = 0; r < 4; r++) oacc[nd][r] *= al;
    }
    lrun += ssum;

    // pack P tiles (B-operand == C-layout)
    bf16x4 pB[4];
#pragma unroll
    for (int nt = 0; nt < 4; nt++) {
      bf16x4 pk = {(__bf16)st[nt][0], (__bf16)st[nt][1],
                   (__bf16)st[nt][2], (__bf16)st[nt][3]};
      pB[nt] = pk;
    }

    // O^T += V^T P^T ; one 16B V frag feeds key-subtiles 2tp and 2tp+1
    __builtin_amdgcn_s_setprio(1);
#pragma unroll
    for (int tp = 0; tp < 2; tp++) {
      const int chv = (tp * 4 + quad) ^ (l15 & 7);
#pragma unroll
      for (int nd = 0; nd < 4; nd++) {
        bf16x8 v8 =
            *(const bf16x8*)(&Vs[cur][(nd * 16 + l15) * 64 + chv * 8]);
        bf16x4 vA0 = {v8[0], v8[1], v8[2], v8[3]};
        bf16x4 vA1 = {v8[4], v8[5], v8[6], v8[7]};
        oacc[nd] = mfma_pv(vA0, pB[2 * tp], oacc[nd]);
        oacc[nd] = mfma_pv(vA1, pB[2 * tp + 1], oacc[nd]);
      }
    }
    __builtin_amdgcn_s_setprio(0);

    __builtin_amdgcn_s_barrier();  // all waves done reading buf cur
  };

  // 2x-unrolled chunk loop: buffer index static per body (chunk c -> c&1)
  for (int c = 0; c <= jb; c += 2) {
    CHUNK(c, 0);
    if (c + 1 <= jb) CHUNK(c + 1, 1);
  }

  // deferred cross-quad l reduction (once per strip instead of per chunk)
  lrun += __shfl_xor(lrun, 16, 64);
  lrun += __shfl_xor(lrun, 32, 64);

  // epilogue: direct normalize + store (no merge).
  const float linv = 1.0f / lrun;
#pragma unroll
  for (int nd = 0; nd < 4; nd++) {
    bf16x4 o = {(__bf16)(oacc[nd][0] * linv), (__bf16)(oacc[nd][1] * linv),
                (__bf16)(oacc[nd][2] * linv), (__bf16)(oacc[nd][3] * linv)};
    *(bf16x4*)(ctx + ((size_t)(b * 2048 + qrow)) * 1024 + h * 64 + nd * 16 +
               quad * 4) = o;
  }
}

// ---------------------------------------------------------------------------
extern "C" void kernel_launch(void* const* d_in, const int* in_sizes, int n_in,
                              void* d_out, int out_size, void* d_ws, size_t ws_size,
                              hipStream_t stream) {
  const float* x  = (const float*)d_in[0];
  const int*   am = (const int*)d_in[1];
  const float* Wq = (const float*)d_in[2];
  const float* bq = (const float*)d_in[3];
  const float* Aq = (const float*)d_in[4];
  const float* Bq = (const float*)d_in[5];
  const float* Wp = (const float*)d_in[6];
  const float* bp = (const float*)d_in[7];
  const float* Ap = (const float*)d_in[8];
  const float* Bp = (const float*)d_in[9];

  __bf16* wqkvT = (__bf16*)d_ws;                       // [3072][1024]
  __bf16* wpT   = wqkvT + (size_t)3072 * 1024;         // [1024][1024]
  __bf16* xbf   = wpT   + (size_t)1024 * 1024;         // [4096][1024]
  __bf16* qbuf  = xbf   + (size_t)4096 * 1024;         // [2][16][2048][64] (+kbuf)
  __bf16* vtbuf = qbuf  + (size_t)2 * 4194304;         // [2][16][64][2048] permuted
  __bf16* ctxb  = vtbuf + (size_t)4194304;             // [4096][1024]

  fold_cast<<<5120, 256, 0, stream>>>(Wq, Aq, Bq, wqkvT, Wp, Ap, Bp, wpT,
                                      x, xbf);

  gemm_qkv<<<dim3(32, 24), 256, 0, stream>>>(wqkvT, xbf, bq, qbuf, vtbuf);
  flash_attn<<<1024, 256, 0, stream>>>(qbuf, qbuf + 4194304, vtbuf, am, ctxb);
  gemm_proj<<<dim3(32, 16), 256, 0, stream>>>(ctxb, wpT, bp, (float*)d_out, 1024);
}